// Round 1
// baseline (129.055 us; speedup 1.0000x reference)
//
#include <hip/hip_runtime.h>
#include <math.h>

#define H 4
#define HD 64
#define NN 1024
#define BB 8
#define FIN 256
#define FOUT 256

typedef _Float16 f16x8 __attribute__((ext_vector_type(8)));
typedef _Float16 f16x4 __attribute__((ext_vector_type(4)));
typedef _Float16 f16x2 __attribute__((ext_vector_type(2)));
typedef float f32x4 __attribute__((ext_vector_type(4)));

// ---------------------------------------------------------------------------
// Kernel 0: WT[f][k] = (fp16) W[k][f] in 64x64 tiles. 16 blocks only —
// the 32 MB adj packing pass moved into attn (overlapped, not serialized).
// ---------------------------------------------------------------------------
__global__ __launch_bounds__(256) void prep_w(const float* __restrict__ W,
                                              _Float16* __restrict__ WT) {
  __shared__ float tile[64][68];
  const int tid = threadIdx.x;
  const int bx = blockIdx.x;
  const int k0 = (bx & 3) * 64, f0 = (bx >> 2) * 64;
  const int r = tid >> 4, c4 = (tid & 15) * 4;
#pragma unroll
  for (int p = 0; p < 4; ++p) {
    float4 v = *(const float4*)&W[(size_t)(k0 + p * 16 + r) * FOUT + f0 + c4];
    *(float4*)&tile[p * 16 + r][c4] = v;
  }
  __syncthreads();
  const int f = tid >> 2, kg = (tid & 3) * 16;
#pragma unroll
  for (int i = 0; i < 4; ++i) {
    f16x4 o;
#pragma unroll
    for (int j = 0; j < 4; ++j) o[j] = (_Float16)tile[kg + i * 4 + j][f];
    *(f16x4*)&WT[(size_t)(f0 + f) * FIN + k0 + kg + i * 4] = o;
  }
}

// ---------------------------------------------------------------------------
// Kernel 1: h = x @ W via fp16 MFMA. Block = 64 rows x 1 head, 512 blocks.
// LDS-free: A-frags built directly from global x (each element read exactly
// once — the old LDS stage had zero reuse). No barriers.
// Epilogue fuses scores: s1, s2, u=exp(s2), v=exp(0.2*s2).
// ---------------------------------------------------------------------------
__global__ __launch_bounds__(256) void gemm_xw(const float* __restrict__ x,
                                               const _Float16* __restrict__ WT,
                                               const float* __restrict__ a,
                                               _Float16* __restrict__ hT,
                                               float* __restrict__ s1_ws,
                                               float* __restrict__ s2_ws,
                                               float* __restrict__ u_ws,
                                               float* __restrict__ v_ws) {
  const int tid = threadIdx.x;
  const int lane = tid & 63, w = tid >> 6;
  const int c = lane & 15, q = lane >> 4;
  const int bn0 = blockIdx.x * 64;
  const int head = blockIdx.y;
  const int b = bn0 >> 10, nb = bn0 & 1023;
  const int bh = b * H + head;

  const _Float16* wbase = WT + (size_t)head * 64 * FIN;
  const float* xrow = x + (size_t)(bn0 + w * 16 + c) * FIN;

  // Issue all 16 x loads up front (same register budget as old staging v[16]).
  float4 xa[16];
#pragma unroll
  for (int ks = 0; ks < 8; ++ks) {
    xa[2 * ks] = *(const float4*)&xrow[ks * 32 + q * 8];
    xa[2 * ks + 1] = *(const float4*)&xrow[ks * 32 + q * 8 + 4];
  }

  f32x4 acc[4];
#pragma unroll
  for (int t = 0; t < 4; ++t) acc[t] = (f32x4){0.f, 0.f, 0.f, 0.f};

#pragma unroll
  for (int ks = 0; ks < 8; ++ks) {
    float4 u0 = xa[2 * ks], u1 = xa[2 * ks + 1];
    f16x8 af;
    af[0] = (_Float16)u0.x; af[1] = (_Float16)u0.y;
    af[2] = (_Float16)u0.z; af[3] = (_Float16)u0.w;
    af[4] = (_Float16)u1.x; af[5] = (_Float16)u1.y;
    af[6] = (_Float16)u1.z; af[7] = (_Float16)u1.w;
#pragma unroll
    for (int t = 0; t < 4; ++t) {
      f16x8 bf = *(const f16x8*)&wbase[(size_t)(t * 16 + c) * FIN + ks * 32 + q * 8];
      acc[t] = __builtin_amdgcn_mfma_f32_16x16x32_f16(af, bf, acc[t], 0, 0, 0);
    }
  }

  float a1v[4], a2v[4];
#pragma unroll
  for (int t = 0; t < 4; ++t) {
    a1v[t] = a[head * 2 * HD + t * 16 + c];
    a2v[t] = a[head * 2 * HD + HD + t * 16 + c];
  }
  float s1p[4] = {0.f, 0.f, 0.f, 0.f};
  float s2p[4] = {0.f, 0.f, 0.f, 0.f};
#pragma unroll
  for (int t = 0; t < 4; ++t) {
    f16x4 hv;
#pragma unroll
    for (int rr = 0; rr < 4; ++rr) {
      hv[rr] = (_Float16)acc[t][rr];
      s1p[rr] += acc[t][rr] * a1v[t];
      s2p[rr] += acc[t][rr] * a2v[t];
    }
    *(f16x4*)&hT[((size_t)(bh * 64 + t * 16 + c)) * NN + nb + w * 16 + q * 4] = hv;
  }
#pragma unroll
  for (int rr = 0; rr < 4; ++rr) {
    float s1 = s1p[rr], s2 = s2p[rr];
#pragma unroll
    for (int off = 8; off; off >>= 1) {
      s1 += __shfl_xor(s1, off);
      s2 += __shfl_xor(s2, off);
    }
    if (c == 0) {
      int n = nb + w * 16 + q * 4 + rr;
      size_t idx = (size_t)bh * NN + n;
      s1_ws[idx] = s1;
      s2_ws[idx] = s2;
      u_ws[idx] = __expf(s2);
      v_ws[idx] = __expf(0.2f * s2);
    }
  }
}

// ---------------------------------------------------------------------------
// Kernel 2: attention. Block = 32 n-rows x (b,h); 1024 blocks, 4 waves.
// adj packed in-kernel (raw int32 -> 1 bit, in-register, then LDS) so the
// 32 MB adj stream overlaps compute instead of being a serialized pre-pass.
// Rank-1 score factorization; software-pipelined p tiles + MFMA.
// ---------------------------------------------------------------------------
__global__ __launch_bounds__(256) void attn(const _Float16* __restrict__ hT,
                                            const float* __restrict__ s1_ws,
                                            const float* __restrict__ s2_ws,
                                            const float* __restrict__ u_ws,
                                            const float* __restrict__ v_ws,
                                            const int* __restrict__ adj,
                                            float* __restrict__ out) {
  __shared__ float s2r[NN], uu[NN], vv[NN];  // 12 KB
  __shared__ _Float16 pt[2][32][136];        // 17 KB
  __shared__ unsigned adjW[32][32];          // 4 KB packed mask
  __shared__ float invL[32];
  const int tid = threadIdx.x, lane = tid & 63, w = tid >> 6;
  const int c = lane & 15, q = lane >> 4;
  const int ntile = blockIdx.x, bh = blockIdx.y;
  const int b = bh >> 2, head = bh & 3;
  const int n0 = ntile * 32;

  {
    size_t base = (size_t)bh * NN + tid * 4;
    *(float4*)&s2r[tid * 4] = *(const float4*)&s2_ws[base];
    *(float4*)&uu[tid * 4] = *(const float4*)&u_ws[base];
    *(float4*)&vv[tid * 4] = *(const float4*)&v_ws[base];
  }
  {
    // Pack this block's 32x1024 adj slice: thread -> (row = tid>>3, m-segment
    // of 128 cols = tid&7). 32 int4 loads -> 4 packed words -> one uint4 store.
    const int row = tid >> 3, seg = tid & 7;
    const int4* ap = (const int4*)&adj[((size_t)(b * NN + n0 + row)) * NN + seg * 128];
    unsigned wds[4];
#pragma unroll
    for (int wi = 0; wi < 4; ++wi) {
      int4 vb[8];
#pragma unroll
      for (int i = 0; i < 8; ++i) vb[i] = ap[wi * 8 + i];
      unsigned bits = 0;
#pragma unroll
      for (int i = 0; i < 8; ++i) {
        bits |= (vb[i].x != 0 ? 1u : 0u) << (4 * i);
        bits |= (vb[i].y != 0 ? 2u : 0u) << (4 * i);
        bits |= (vb[i].z != 0 ? 4u : 0u) << (4 * i);
        bits |= (vb[i].w != 0 ? 8u : 0u) << (4 * i);
      }
      wds[wi] = bits;
    }
    *(uint4*)&adjW[row][seg * 4] = make_uint4(wds[0], wds[1], wds[2], wds[3]);
  }
  __syncthreads();

  float s1v[8];
#pragma unroll
  for (int r = 0; r < 8; ++r) s1v[r] = s1_ws[(size_t)bh * NN + n0 + w * 8 + r];

  const int wc = lane >> 4;          // word within the 128-m chunk
  const int shft = (2 * lane) & 31;  // bit position of m = 2*lane

  // ---- pass 1: masked max of s2 per row (mask bits from LDS) ----
  float mx[8];
#pragma unroll
  for (int r = 0; r < 8; ++r) mx[r] = -INFINITY;
#pragma unroll
  for (int ch = 0; ch < 8; ++ch) {
    float2 s2p = *(const float2*)&s2r[ch * 128 + 2 * lane];
#pragma unroll
    for (int r = 0; r < 8; ++r) {
      unsigned bits = adjW[w * 8 + r][ch * 4 + wc] >> shft;
      mx[r] = fmaxf(mx[r], (bits & 1u) ? s2p.x : -INFINITY);
      mx[r] = fmaxf(mx[r], (bits & 2u) ? s2p.y : -INFINITY);
    }
  }
  float Arow[8], Brow[8], ns1[8];
#pragma unroll
  for (int r = 0; r < 8; ++r) {
    float m = mx[r];
#pragma unroll
    for (int off = 32; off; off >>= 1) m = fmaxf(m, __shfl_xor(m, off));
    float t0 = s1v[r] + m;
    float M = fmaxf(t0, 0.2f * t0);  // lrelu (monotone => exact row max)
    Arow[r] = __expf(s1v[r] - M);
    Brow[r] = __expf(0.2f * s1v[r] - M);
    ns1[r] = -s1v[r];
  }

  // ---- pass 2: software-pipelined p tiles + MFMA ----
  float Lp[8];
#pragma unroll
  for (int r = 0; r < 8; ++r) Lp[r] = 0.f;
  f32x4 acc[2];
  acc[0] = (f32x4){0.f, 0.f, 0.f, 0.f};
  acc[1] = (f32x4){0.f, 0.f, 0.f, 0.f};
  const _Float16* bptr = hT + ((size_t)bh * 64 + w * 16 + c) * NN + q * 8;

  // prefetch chunk 0 B-frags
  f16x8 nbf0 = *(const f16x8*)(bptr);
  f16x8 nbf1 = *(const f16x8*)(bptr + 32);
  f16x8 nbf2 = *(const f16x8*)(bptr + 64);
  f16x8 nbf3 = *(const f16x8*)(bptr + 96);

  for (int ch = 0; ch < 8; ++ch) {
    const int buf = ch & 1;
    f16x8 bf0 = nbf0, bf1 = nbf1, bf2 = nbf2, bf3 = nbf3;
    float2 s2p = *(const float2*)&s2r[ch * 128 + 2 * lane];
    float2 up = *(const float2*)&uu[ch * 128 + 2 * lane];
    float2 vp = *(const float2*)&vv[ch * 128 + 2 * lane];
#pragma unroll
    for (int r = 0; r < 8; ++r) {
      unsigned bits = adjW[w * 8 + r][ch * 4 + wc] >> shft;
      float p0 = (s2p.x >= ns1[r]) ? Arow[r] * up.x : Brow[r] * vp.x;
      float p1 = (s2p.y >= ns1[r]) ? Arow[r] * up.y : Brow[r] * vp.y;
      p0 = (bits & 1u) ? p0 : 0.f;
      p1 = (bits & 2u) ? p1 : 0.f;
      Lp[r] += p0 + p1;
      f16x2 pk = __builtin_bit_cast(f16x2, __builtin_amdgcn_cvt_pkrtz(p0, p1));
      *(f16x2*)&pt[buf][w * 8 + r][2 * lane] = pk;
    }
    if (ch < 7) {  // issue next chunk's B-frags; consumed after NEXT barrier
      nbf0 = *(const f16x8*)(bptr + (ch + 1) * 128);
      nbf1 = *(const f16x8*)(bptr + (ch + 1) * 128 + 32);
      nbf2 = *(const f16x8*)(bptr + (ch + 1) * 128 + 64);
      nbf3 = *(const f16x8*)(bptr + (ch + 1) * 128 + 96);
    }
    __syncthreads();
#pragma unroll
    for (int t = 0; t < 2; ++t) {
      f16x8 a0 = *(const f16x8*)&pt[buf][t * 16 + c][q * 8];
      f16x8 a1 = *(const f16x8*)&pt[buf][t * 16 + c][32 + q * 8];
      f16x8 a2 = *(const f16x8*)&pt[buf][t * 16 + c][64 + q * 8];
      f16x8 a3 = *(const f16x8*)&pt[buf][t * 16 + c][96 + q * 8];
      acc[t] = __builtin_amdgcn_mfma_f32_16x16x32_f16(a0, bf0, acc[t], 0, 0, 0);
      acc[t] = __builtin_amdgcn_mfma_f32_16x16x32_f16(a1, bf1, acc[t], 0, 0, 0);
      acc[t] = __builtin_amdgcn_mfma_f32_16x16x32_f16(a2, bf2, acc[t], 0, 0, 0);
      acc[t] = __builtin_amdgcn_mfma_f32_16x16x32_f16(a3, bf3, acc[t], 0, 0, 0);
    }
  }

  // ---- epilogue ----
  float myL = 0.f;
#pragma unroll
  for (int r = 0; r < 8; ++r) {
    float s = Lp[r];
#pragma unroll
    for (int off = 32; off; off >>= 1) s += __shfl_xor(s, off);
    if (lane == r) myL = s;
  }
  if (lane < 8) invL[w * 8 + lane] = 1.0f / myL;
  __syncthreads();
#pragma unroll
  for (int t = 0; t < 2; ++t) {
#pragma unroll
    for (int rr = 0; rr < 4; ++rr) {
      int nloc = t * 16 + q * 4 + rr;
      out[((size_t)(b * NN + n0 + nloc)) * FOUT + head * 64 + w * 16 + c] =
          acc[t][rr] * invL[nloc];
    }
  }
}

extern "C" void kernel_launch(void* const* d_in, const int* in_sizes, int n_in,
                              void* d_out, int out_size, void* d_ws, size_t ws_size,
                              hipStream_t stream) {
  const float* x = (const float*)d_in[0];
  const int* adj = (const int*)d_in[1];
  const float* W = (const float*)d_in[2];
  const float* a = (const float*)d_in[3];
  float* out = (float*)d_out;

  char* ws = (char*)d_ws;
  _Float16* hT = (_Float16*)ws;                              // 4 MB
  _Float16* WT = (_Float16*)(ws + (size_t)4 * 1024 * 1024);  // 128 KB
  float* s1_ws = (float*)(ws + (size_t)4 * 1024 * 1024 + 128 * 1024);
  float* s2_ws = s1_ws + (size_t)BB * H * NN;
  float* u_ws = s2_ws + (size_t)BB * H * NN;
  float* v_ws = u_ws + (size_t)BB * H * NN;

  prep_w<<<16, 256, 0, stream>>>(W, WT);
  gemm_xw<<<dim3(128, 4), 256, 0, stream>>>(x, WT, a, hT, s1_ws, s2_ws, u_ws, v_ws);
  attn<<<dim3(32, 32), 256, 0, stream>>>(hT, s1_ws, s2_ws, u_ws, v_ws, adj, out);
}